// Round 6
// baseline (2138.751 us; speedup 1.0000x reference)
//
#include <hip/hip_runtime.h>

#define SEQ 512
#define BATCH 256
#define INDIM 256
#define MLP 128
#define M_ROWS (SEQ * BATCH)        // 131072
#define PRE_STRIDE 136              // 128 mlp-pre + 4 gate-pre + 4 pad
#define AUX_OFF ((size_t)M_ROWS * PRE_STRIDE)  // in floats

// ---------------------------------------------------------------------------
// Kernel 1: prep — column sums of the recurrent halves of W1 and gate weights.
// ---------------------------------------------------------------------------
__global__ __launch_bounds__(256) void prep_kernel(
    const float* __restrict__ W1,
    const float* __restrict__ Wf, const float* __restrict__ Wi,
    const float* __restrict__ Wg, const float* __restrict__ Wo,
    const float* __restrict__ bf, const float* __restrict__ bi,
    const float* __restrict__ bg, const float* __restrict__ bo,
    float* __restrict__ aux) {
  const int tid = threadIdx.x;
  if (tid < 128) {
    float s = 0.f;
    for (int k = 0; k < 256; ++k) s += W1[(size_t)(256 + k) * 128 + tid];
    aux[tid] = s;
  } else if (tid < 132) {
    const int g = tid - 128;
    const float* w = (g == 0) ? Wf : (g == 1) ? Wi : (g == 2) ? Wg : Wo;
    float s = 0.f;
    for (int k = 0; k < 256; ++k) s += w[256 + k];
    aux[128 + g] = s;
  } else if (tid < 136) {
    const int g = tid - 132;
    const float* bp = (g == 0) ? bf : (g == 1) ? bi : (g == 2) ? bg : bo;
    aux[132 + g] = bp[0];
  }
}

// ---------------------------------------------------------------------------
// Kernel 2: fp32 GEMM, restructured: BK=32, global_load_lds (direct-to-LDS,
// 16B width), double-buffered LDS. The __syncthreads vmcnt(0) drain now waits
// on loads issued one full chunk (~4000 cyc) earlier -> essentially free.
// 256 threads, BM=128, BN=128 (+4 fused gate cols), 8x8 acc/thread,
// 2 blocks/CU (64KB LDS).
// ---------------------------------------------------------------------------
#define GBK 32

__device__ __forceinline__ void gl_lds16(const float* g, float* lds) {
  __builtin_amdgcn_global_load_lds(
      (const __attribute__((address_space(1))) void*)g,
      (__attribute__((address_space(3))) void*)lds, 16, 0, 0);
}

__global__ __launch_bounds__(256, 2) void gemm_kernel(
    const float* __restrict__ X,    // [M_ROWS][256]
    const float* __restrict__ W1,   // [512][128] (rows 0..255 used)
    const float* __restrict__ b1p,  // [128]
    const float* __restrict__ Wf, const float* __restrict__ Wi,
    const float* __restrict__ Wg, const float* __restrict__ Wo,
    const float* __restrict__ bfp, const float* __restrict__ bip,
    const float* __restrict__ bgp, const float* __restrict__ bop,
    float* __restrict__ PRE) {
  // LDS layouts are EXACTLY the load order (global_load_lds constraint):
  // Xs[bb]: [row 0..127][k 0..31] contiguous; Ws[bb]: [kk 0..31][n 0..127].
  __shared__ __align__(16) float Xs[2][128 * GBK];
  __shared__ __align__(16) float Ws[2][GBK * 128];
  __shared__ float Wgs[2][GBK * 4];

  const int tid = threadIdx.x;
  const int wave = tid >> 6, lane = tid & 63;
  const int tx = tid & 15, ty = tid >> 4;
  const int r2 = tid >> 1, gp = (tid & 1) * 2;
  const size_t rowbase = (size_t)blockIdx.x * 128;

  const int gsel = tid & 3;
  const float* gsrc = (gsel == 0) ? Wf : (gsel == 1) ? Wi : (gsel == 2) ? Wg : Wo;

  float acc[8][8] = {};
  float ga = 0.f, gb = 0.f;
  float gateval = 0.f;

  // ---- stage chunk kc into buffer bb (async, direct to LDS) ----
  auto stage = [&](int kc, int bb) {
#pragma unroll
    for (int it = 0; it < 4; ++it) {
      const int ub = wave * 256 + it * 64;
      const int u = ub + lane;
      const float* gx = &X[(rowbase + (u >> 3)) * 256 + kc + (u & 7) * 4];
      gl_lds16(gx, &Xs[bb][ub * 4]);
    }
#pragma unroll
    for (int it = 0; it < 4; ++it) {
      const int ub = wave * 256 + it * 64;
      const int u = ub + lane;
      const float* gw = &W1[(size_t)kc * 128 + u * 4];
      gl_lds16(gw, &Ws[bb][ub * 4]);
    }
  };

  // prologue: chunk 0
  stage(0, 0);
  if (tid < 128) gateval = gsrc[tid >> 2];
  if (tid < 128) Wgs[0][tid] = gateval;
  __syncthreads();

  for (int c = 0; c < 8; ++c) {
    const int bb = c & 1, nb = bb ^ 1;
    if (c < 7) {
      stage((c + 1) * GBK, nb);
      if (tid < 128) gateval = gsrc[(c + 1) * GBK + (tid >> 2)];
    }
    const float* xs = &Xs[bb][0];
    const float* ws = &Ws[bb][0];
    const float* wg = &Wgs[bb][0];
#pragma unroll
    for (int k4 = 0; k4 < GBK / 4; ++k4) {
      float4 a[8];
#pragma unroll
      for (int i = 0; i < 8; ++i)
        a[i] = *(const float4*)&xs[(ty * 8 + i) * GBK + k4 * 4];
#pragma unroll
      for (int ks = 0; ks < 4; ++ks) {
        const int kk = k4 * 4 + ks;
        const float4 b0 = *(const float4*)&ws[kk * 128 + tx * 8];
        const float4 b1 = *(const float4*)&ws[kk * 128 + tx * 8 + 4];
        const float bv[8] = {b0.x, b0.y, b0.z, b0.w, b1.x, b1.y, b1.z, b1.w};
#pragma unroll
        for (int i = 0; i < 8; ++i) {
          const float av = (ks == 0) ? a[i].x : (ks == 1) ? a[i].y
                          : (ks == 2) ? a[i].z : a[i].w;
#pragma unroll
          for (int j = 0; j < 8; ++j)
            acc[i][j] = fmaf(av, bv[j], acc[i][j]);
        }
        const float xv = xs[r2 * GBK + kk];
        ga = fmaf(xv, wg[kk * 4 + gp], ga);
        gb = fmaf(xv, wg[kk * 4 + gp + 1], gb);
      }
    }
    if (c < 7 && tid < 128) Wgs[nb][tid] = gateval;
    __syncthreads();
  }

  // epilogue: add b1 and store mlp pre-activations
  float bias[8];
  {
    const float4 u0 = *(const float4*)&b1p[tx * 8];
    const float4 u1 = *(const float4*)&b1p[tx * 8 + 4];
    bias[0] = u0.x; bias[1] = u0.y; bias[2] = u0.z; bias[3] = u0.w;
    bias[4] = u1.x; bias[5] = u1.y; bias[6] = u1.z; bias[7] = u1.w;
  }
#pragma unroll
  for (int i = 0; i < 8; ++i) {
    const size_t row = rowbase + ty * 8 + i;
    float4 o0, o1;
    o0.x = acc[i][0] + bias[0]; o0.y = acc[i][1] + bias[1];
    o0.z = acc[i][2] + bias[2]; o0.w = acc[i][3] + bias[3];
    o1.x = acc[i][4] + bias[4]; o1.y = acc[i][5] + bias[5];
    o1.z = acc[i][6] + bias[6]; o1.w = acc[i][7] + bias[7];
    *(float4*)&PRE[row * PRE_STRIDE + tx * 8] = o0;
    *(float4*)&PRE[row * PRE_STRIDE + tx * 8 + 4] = o1;
  }
  {
    const float bf0 = bfp[0], bi0 = bip[0], bg0 = bgp[0], bo0 = bop[0];
    const float ab = (gp == 0) ? bf0 : bg0;
    const float bb2 = (gp == 0) ? bi0 : bo0;
    const size_t row = rowbase + r2;
    float2 og;
    og.x = ga + ab; og.y = gb + bb2;
    *(float2*)&PRE[row * PRE_STRIDE + 128 + gp] = og;
  }
}

// ---------------------------------------------------------------------------
// Kernel 3: serial recurrence. R5 post-mortem: VALU only ~250 cyc/step of
// 2270; latency chain ~1150; remaining ~1100 attributed to per-step vmcnt
// waits (rotating prefetch + unwaited store force conservative waits on the
// previous step's store retire). Fix: block-of-8 register prefetch — inside
// a block of 8 steps there are NO vmem value-uses, so no waits; the single
// wait sits at the block rotation, amortized 8x.
// ---------------------------------------------------------------------------
__device__ __forceinline__ void lds_fence_wave() {
  asm volatile("s_waitcnt lgkmcnt(0)" ::: "memory");
}

__device__ __forceinline__ float sigmoid_f(float x) {
  return __fdividef(1.0f, 1.0f + __expf(-x));
}
__device__ __forceinline__ float tanh_f(float x) {
  const float e = __expf(-2.0f * x);
  return __fdividef(1.0f - e, 1.0f + e);
}

__global__ __attribute__((amdgpu_waves_per_eu(1, 1))) __launch_bounds__(64)
void rec_kernel(
    const float* __restrict__ PRE, const float* __restrict__ W2,
    const float* __restrict__ b2, const float* __restrict__ aux,
    float* __restrict__ out) {
  __shared__ __align__(16) float h1s[128];

  const int l = threadIdx.x;
  const int b = blockIdx.x;
  const int m = l & 31, half = l >> 5;
  const int g = m >> 3;           // gate group: 0=f 1=i 2=g 3=o
  const int gbase = g * 8;

  // W2 fragment in registers: lane (m,half) holds W2[half*64+u][m]
  float w2r[64];
#pragma unroll
  for (int u = 0; u < 64; ++u) w2r[u] = W2[(size_t)(half * 64 + u) * 32 + m];
  const float b2v = b2[m];
  const float2 s1 = *(const float2*)&aux[2 * l];
  const float4 sg = *(const float4*)&aux[128];  // sf, si, sg, so

  float h = 0.f, c = 0.f;

  const float* pr0 = PRE + (size_t)b * PRE_STRIDE;
  const size_t ts = (size_t)BATCH * PRE_STRIDE;

  // block-of-8 prefetch: current block in pc/gc, next in pn/gn
  float2 pc[8]; float4 gc[8];
#pragma unroll
  for (int u = 0; u < 8; ++u) {
    pc[u] = *(const float2*)(pr0 + (size_t)u * ts + 2 * l);
    gc[u] = *(const float4*)(pr0 + (size_t)u * ts + 128);
  }

  const float4* h1p = (const float4*)&h1s[half * 64];

  for (int blk = 0; blk < 64; ++blk) {
    const int tnb = (blk < 63) ? (blk + 1) : 63;
    float2 pn[8]; float4 gn[8];
#pragma unroll
    for (int u = 0; u < 8; ++u) {
      const float* base = pr0 + (size_t)(tnb * 8 + u) * ts;
      pn[u] = *(const float2*)(base + 2 * l);
      gn[u] = *(const float4*)(base + 128);
    }

#pragma unroll
    for (int u = 0; u < 8; ++u) {
      const int t = blk * 8 + u;
      const float2 p0 = pc[u];
      const float4 g0 = gc[u];

      // h1 = relu(pre + h*s1)
      const float h10 = fmaxf(fmaf(h, s1.x, p0.x), 0.f);
      const float h11 = fmaxf(fmaf(h, s1.y, p0.y), 0.f);
      // classical gates (independent of matvec — overlaps LDS latency)
      const float zf = fmaf(h, sg.x, g0.x);
      const float zi = fmaf(h, sg.y, g0.y);
      const float zg = fmaf(h, sg.z, g0.z);
      const float zo = fmaf(h, sg.w, g0.w);
      const float cf = sigmoid_f(zf);
      const float ci = sigmoid_f(zi);
      const float cg = tanh_f(zg);
      const float co = sigmoid_f(zo);

      // the only LDS roundtrip: broadcast h1
      ((float2*)h1s)[l] = make_float2(h10, h11);
      lds_fence_wave();

      float q0 = 0.f, q1 = 0.f, q2 = 0.f, q3 = 0.f;
#pragma unroll
      for (int jj = 0; jj < 16; ++jj) {
        const float4 hv = h1p[jj];
        q0 = fmaf(hv.x, w2r[4 * jj + 0], q0);
        q1 = fmaf(hv.y, w2r[4 * jj + 1], q1);
        q2 = fmaf(hv.z, w2r[4 * jj + 2], q2);
        q3 = fmaf(hv.w, w2r[4 * jj + 3], q3);
      }
      const float qh = (q0 + q1) + (q2 + q3);
      const float theta = qh + __shfl_xor(qh, 32, 64) + b2v;
      const float cv = __cosf(theta);

      // gather my gate group's 8 cos values (one latency event)
      const float e0 = __shfl(cv, gbase + 0, 64);
      const float e1 = __shfl(cv, gbase + 1, 64);
      const float e2 = __shfl(cv, gbase + 2, 64);
      const float e3 = __shfl(cv, gbase + 3, 64);
      const float e4 = __shfl(cv, gbase + 4, 64);
      const float e5 = __shfl(cv, gbase + 5, 64);
      const float e6 = __shfl(cv, gbase + 6, 64);
      const float e7 = __shfl(cv, gbase + 7, 64);
      float p = e0, s = e0;
      p *= e1; s += p;
      p *= e2; s += p;
      p *= e3; s += p;
      p *= e4; s += p;
      p *= e5; s += p;
      p *= e6; s += p;
      p *= e7; s += p;
      const float qv = s * 0.125f;

      // one quantum activation per lane (group 2: tanh = 2*sigmoid(2x)-1)
      const float qarg = (g == 2) ? (2.0f * qv) : qv;
      const float qs = sigmoid_f(qarg);
      const float av = (g == 2) ? (2.0f * qs - 1.0f) : qs;

      const float aF = __shfl(av, 0, 64);
      const float aI = __shfl(av, 8, 64);
      const float aG = __shfl(av, 16, 64);
      const float aO = __shfl(av, 24, 64);

      const float f  = 0.5f * (cf + aF);
      const float ii = 0.5f * (ci + aI);
      const float gg = 0.5f * (cg + aG);
      const float oo = 0.5f * (co + aO);

      c = fmaf(f, c, ii * gg);
      h = oo * tanh_f(c);

      float4 hv4o; hv4o.x = h; hv4o.y = h; hv4o.z = h; hv4o.w = h;
      *(float4*)(out + ((size_t)t * BATCH + b) * 256 + 4 * l) = hv4o;
    }

#pragma unroll
    for (int u = 0; u < 8; ++u) { pc[u] = pn[u]; gc[u] = gn[u]; }
  }

  // final (hx, cx) outputs
  float4 hq; hq.x = h; hq.y = h; hq.z = h; hq.w = h;
  float4 cq; cq.x = c; cq.y = c; cq.z = c; cq.w = c;
  *(float4*)(out + (size_t)SEQ * BATCH * 256 + (size_t)b * 256 + 4 * l) = hq;
  *(float4*)(out + (size_t)SEQ * BATCH * 256 + (size_t)BATCH * 256 +
             (size_t)b * 256 + 4 * l) = cq;
}

// ---------------------------------------------------------------------------
extern "C" void kernel_launch(void* const* d_in, const int* in_sizes, int n_in,
                              void* d_out, int out_size, void* d_ws,
                              size_t ws_size, hipStream_t stream) {
  const float* X  = (const float*)d_in[0];
  const float* W1 = (const float*)d_in[1];
  const float* b1 = (const float*)d_in[2];
  const float* W2 = (const float*)d_in[3];
  const float* b2 = (const float*)d_in[4];
  const float* Wf = (const float*)d_in[5];
  const float* bf = (const float*)d_in[6];
  const float* Wi = (const float*)d_in[7];
  const float* bi = (const float*)d_in[8];
  const float* Wg = (const float*)d_in[9];
  const float* bg = (const float*)d_in[10];
  const float* Wo = (const float*)d_in[11];
  const float* bo = (const float*)d_in[12];

  float* ws  = (float*)d_ws;
  float* PRE = ws;
  float* aux = ws + AUX_OFF;
  float* out = (float*)d_out;

  prep_kernel<<<1, 256, 0, stream>>>(W1, Wf, Wi, Wg, Wo, bf, bi, bg, bo, aux);
  gemm_kernel<<<M_ROWS / 128, 256, 0, stream>>>(X, W1, b1, Wf, Wi, Wg, Wo,
                                                bf, bi, bg, bo, PRE);
  rec_kernel<<<BATCH, 64, 0, stream>>>(PRE, W2, b2, aux, out);
}

// Round 7
// 1104.664 us; speedup vs baseline: 1.9361x; 1.9361x over previous
//
#include <hip/hip_runtime.h>

#define SEQ 512
#define BATCH 256
#define INDIM 256
#define MLP 128
#define M_ROWS (SEQ * BATCH)        // 131072
#define PRE_STRIDE 136              // 128 mlp-pre + 4 gate-pre + 4 pad
#define AUX_OFF ((size_t)M_ROWS * PRE_STRIDE)  // in floats

// ---------------------------------------------------------------------------
// Kernel 1: prep — column sums of the recurrent halves of W1 and gate weights.
// ---------------------------------------------------------------------------
__global__ __launch_bounds__(256) void prep_kernel(
    const float* __restrict__ W1,
    const float* __restrict__ Wf, const float* __restrict__ Wi,
    const float* __restrict__ Wg, const float* __restrict__ Wo,
    const float* __restrict__ bf, const float* __restrict__ bi,
    const float* __restrict__ bg, const float* __restrict__ bo,
    float* __restrict__ aux) {
  const int tid = threadIdx.x;
  if (tid < 128) {
    float s = 0.f;
    for (int k = 0; k < 256; ++k) s += W1[(size_t)(256 + k) * 128 + tid];
    aux[tid] = s;
  } else if (tid < 132) {
    const int g = tid - 128;
    const float* w = (g == 0) ? Wf : (g == 1) ? Wi : (g == 2) ? Wg : Wo;
    float s = 0.f;
    for (int k = 0; k < 256; ++k) s += w[256 + k];
    aux[128 + g] = s;
  } else if (tid < 136) {
    const int g = tid - 132;
    const float* bp = (g == 0) ? bf : (g == 1) ? bi : (g == 2) ? bg : bo;
    aux[132 + g] = bp[0];
  }
}

// ---------------------------------------------------------------------------
// Kernel 2: fp32 GEMM. R6 post-mortem: global_load_lds forced a [row][k]
// LDS layout -> 16-way bank conflicts (2e7), and the extra staging arrays
// spilled acc to scratch (FETCH 1.9GB / WRITE 3.7GB of HBM spill traffic).
// Revert to R5's conflict-free padded ds_write staging, and double-buffer:
// global loads for chunk c+1 are issued BEFORE computing chunk c, ds_write
// after — the vmcnt wait lands behind ~1300 cyc of compute. One barrier per
// chunk.
// ---------------------------------------------------------------------------
#define BK 16
#define LDX 132  // padded LDS row stride (words)

__global__ __launch_bounds__(256) void gemm_kernel(
    const float* __restrict__ X,    // [M_ROWS][256]
    const float* __restrict__ W1,   // [512][128] (rows 0..255 used)
    const float* __restrict__ b1p,  // [128]
    const float* __restrict__ Wf, const float* __restrict__ Wi,
    const float* __restrict__ Wg, const float* __restrict__ Wo,
    const float* __restrict__ bfp, const float* __restrict__ bip,
    const float* __restrict__ bgp, const float* __restrict__ bop,
    float* __restrict__ PRE) {
  __shared__ __align__(16) float Xs[2][BK * LDX];   // [kk][row], padded
  __shared__ __align__(16) float Ws[2][BK * LDX];   // [kk][col], padded
  __shared__ float Wgs[2][BK * 4];                  // [kk][gate]

  const int tid = threadIdx.x;
  const int tx = tid & 15, ty = tid >> 4;        // 16x16 compute grid
  const int r_st = tid >> 1, kh = (tid & 1) * 8; // X staging role
  const int wk = tid >> 4, wn = (tid & 15) * 8;  // W staging role
  const int r2 = tid >> 1, gp = (tid & 1) * 2;   // gate compute role
  const size_t rowbase = (size_t)blockIdx.x * 128;

  const int gsel = tid & 3;
  const float* gsrc = (gsel == 0) ? Wf : (gsel == 1) ? Wi
                     : (gsel == 2) ? Wg : Wo;

  float acc[8][8] = {};
  float ga = 0.f, gb = 0.f;

  float4 xa, xb, wa, wb;
  float wgv = 0.f;

  auto gload = [&](int kc) {
    xa = *(const float4*)&X[(rowbase + r_st) * 256 + kc + kh];
    xb = *(const float4*)&X[(rowbase + r_st) * 256 + kc + kh + 4];
    wa = *(const float4*)&W1[(size_t)(kc + wk) * 128 + wn];
    wb = *(const float4*)&W1[(size_t)(kc + wk) * 128 + wn + 4];
    if (tid < 64) wgv = gsrc[kc + (tid >> 2)];
  };
  auto swrite = [&](int bb) {
    Xs[bb][(kh + 0) * LDX + r_st] = xa.x;
    Xs[bb][(kh + 1) * LDX + r_st] = xa.y;
    Xs[bb][(kh + 2) * LDX + r_st] = xa.z;
    Xs[bb][(kh + 3) * LDX + r_st] = xa.w;
    Xs[bb][(kh + 4) * LDX + r_st] = xb.x;
    Xs[bb][(kh + 5) * LDX + r_st] = xb.y;
    Xs[bb][(kh + 6) * LDX + r_st] = xb.z;
    Xs[bb][(kh + 7) * LDX + r_st] = xb.w;
    *(float4*)&Ws[bb][wk * LDX + wn] = wa;
    *(float4*)&Ws[bb][wk * LDX + wn + 4] = wb;
    if (tid < 64) Wgs[bb][tid] = wgv;
  };

  // prologue: chunk 0 staged into buffer 0
  gload(0);
  swrite(0);
  __syncthreads();

  for (int c = 0; c < 16; ++c) {
    const int bb = c & 1;
    if (c < 15) gload((c + 1) * BK);   // issue next chunk's loads (async)

#pragma unroll
    for (int kk = 0; kk < BK; ++kk) {
      const float4 a0 = *(const float4*)&Xs[bb][kk * LDX + ty * 8];
      const float4 a1 = *(const float4*)&Xs[bb][kk * LDX + ty * 8 + 4];
      const float4 c0 = *(const float4*)&Ws[bb][kk * LDX + tx * 8];
      const float4 c1 = *(const float4*)&Ws[bb][kk * LDX + tx * 8 + 4];
      const float av[8] = {a0.x, a0.y, a0.z, a0.w, a1.x, a1.y, a1.z, a1.w};
      const float bv[8] = {c0.x, c0.y, c0.z, c0.w, c1.x, c1.y, c1.z, c1.w};
#pragma unroll
      for (int i = 0; i < 8; ++i)
#pragma unroll
        for (int j = 0; j < 8; ++j)
          acc[i][j] = fmaf(av[i], bv[j], acc[i][j]);
      const float xv = Xs[bb][kk * LDX + r2];
      ga = fmaf(xv, Wgs[bb][kk * 4 + gp], ga);
      gb = fmaf(xv, Wgs[bb][kk * 4 + gp + 1], gb);
    }

    if (c < 15) swrite(bb ^ 1);  // vmcnt wait here — loads are ~1300 cyc old
    __syncthreads();
  }

  // epilogue
  float bias[8];
  {
    const float4 u0 = *(const float4*)&b1p[tx * 8];
    const float4 u1 = *(const float4*)&b1p[tx * 8 + 4];
    bias[0] = u0.x; bias[1] = u0.y; bias[2] = u0.z; bias[3] = u0.w;
    bias[4] = u1.x; bias[5] = u1.y; bias[6] = u1.z; bias[7] = u1.w;
  }
#pragma unroll
  for (int i = 0; i < 8; ++i) {
    const size_t row = rowbase + ty * 8 + i;
    float4 o0, o1;
    o0.x = acc[i][0] + bias[0]; o0.y = acc[i][1] + bias[1];
    o0.z = acc[i][2] + bias[2]; o0.w = acc[i][3] + bias[3];
    o1.x = acc[i][4] + bias[4]; o1.y = acc[i][5] + bias[5];
    o1.z = acc[i][6] + bias[6]; o1.w = acc[i][7] + bias[7];
    *(float4*)&PRE[row * PRE_STRIDE + tx * 8] = o0;
    *(float4*)&PRE[row * PRE_STRIDE + tx * 8 + 4] = o1;
  }
  {
    const float ab = (gp == 0) ? bfp[0] : bgp[0];
    const float bb2 = (gp == 0) ? bip[0] : bop[0];
    float2 og;
    og.x = ga + ab; og.y = gb + bb2;
    *(float2*)&PRE[(rowbase + r2) * PRE_STRIDE + 128 + gp] = og;
  }
}

// ---------------------------------------------------------------------------
// Kernel 3: serial recurrence — TWO batch chains per wave (32 lanes each).
// R6 post-mortem: rec is pinned by per-step latency events (fence + 3 shfl
// stages, ~150 cyc each, nothing to hide them). With lane = one m and full
// K=128 per lane: the shfl_xor reduction DISAPPEARS (each lane owns its dot
// product), and the two chains interleave in one instruction stream, so each
// latency event is shared by 2 steps. Issue cost per step unchanged.
// ---------------------------------------------------------------------------
__device__ __forceinline__ void lds_fence_wave() {
  asm volatile("s_waitcnt lgkmcnt(0)" ::: "memory");
}
__device__ __forceinline__ float sigmoid_f(float x) {
  return __fdividef(1.0f, 1.0f + __expf(-x));
}
__device__ __forceinline__ float tanh_f(float x) {
  const float e = __expf(-2.0f * x);
  return __fdividef(1.0f - e, 1.0f + e);
}

__global__ __attribute__((amdgpu_waves_per_eu(1, 1))) __launch_bounds__(64)
void rec_kernel(
    const float* __restrict__ PRE, const float* __restrict__ W2,
    const float* __restrict__ b2, const float* __restrict__ aux,
    float* __restrict__ out) {
  __shared__ __align__(16) float h1s[2 * 128];  // [hb][j]

  const int l = threadIdx.x;
  const int hb = l >> 5;            // which batch chain in this wave
  const int i = l & 31;             // my output column m
  const int b = blockIdx.x * 2 + hb;
  const int g = i >> 3;             // gate group 0=f 1=i 2=g 3=o
  const int lbase = hb * 32;        // first lane of my chain

  // full-K W2 column in registers: w2r[j] = W2[j][i], j=0..127
  float w2r[128];
#pragma unroll
  for (int j = 0; j < 128; ++j) w2r[j] = W2[(size_t)j * 32 + i];
  const float b2v = b2[i];
  const float4 s1 = *(const float4*)&aux[4 * i];
  const float4 sg = *(const float4*)&aux[128];  // sf, si, sg, so

  float h = 0.f, c = 0.f;

  const float* pr0 = PRE + (size_t)b * PRE_STRIDE;
  const size_t ts = (size_t)BATCH * PRE_STRIDE;

  // depth-3 rotating prefetch: p (my 4 mlp-pre values) + g (4 gate-pres)
  float4 p0 = *(const float4*)(pr0 + 0 * ts + 4 * i);
  float4 g0 = *(const float4*)(pr0 + 0 * ts + 128);
  float4 p1 = *(const float4*)(pr0 + 1 * ts + 4 * i);
  float4 g1 = *(const float4*)(pr0 + 1 * ts + 128);
  float4 p2 = *(const float4*)(pr0 + 2 * ts + 4 * i);
  float4 g2 = *(const float4*)(pr0 + 2 * ts + 128);

  const float4* hp = (const float4*)&h1s[hb * 128];

  for (int t = 0; t < SEQ; ++t) {
    // h1 quad = relu(pre + h*s1)
    const float h10 = fmaxf(fmaf(h, s1.x, p0.x), 0.f);
    const float h11 = fmaxf(fmaf(h, s1.y, p0.y), 0.f);
    const float h12 = fmaxf(fmaf(h, s1.z, p0.z), 0.f);
    const float h13 = fmaxf(fmaf(h, s1.w, p0.w), 0.f);
    // classical gates (redundant across my 32 lanes; overlaps LDS latency)
    const float zf = fmaf(h, sg.x, g0.x);
    const float zi = fmaf(h, sg.y, g0.y);
    const float zg = fmaf(h, sg.z, g0.z);
    const float zo = fmaf(h, sg.w, g0.w);
    const float cf = sigmoid_f(zf);
    const float ci = sigmoid_f(zi);
    const float cg = tanh_f(zg);
    const float co = sigmoid_f(zo);
    // rotate prefetch
    p0 = p1; g0 = g1; p1 = p2; g1 = g2;
    const int tn = (t + 3 < SEQ) ? (t + 3) : (SEQ - 1);
    p2 = *(const float4*)(pr0 + (size_t)tn * ts + 4 * i);
    g2 = *(const float4*)(pr0 + (size_t)tn * ts + 128);

    // the only LDS roundtrip: publish my h1 quad
    float4 hq; hq.x = h10; hq.y = h11; hq.z = h12; hq.w = h13;
    ((float4*)h1s)[l] = hq;
    lds_fence_wave();

    // q[i] = sum_{j=0..127} h1[j] * W2[j][i] — whole dot in one lane
    float q0 = 0.f, q1 = 0.f, q2 = 0.f, q3 = 0.f;
#pragma unroll
    for (int jj = 0; jj < 32; ++jj) {
      const float4 hv = hp[jj];
      q0 = fmaf(hv.x, w2r[4 * jj + 0], q0);
      q1 = fmaf(hv.y, w2r[4 * jj + 1], q1);
      q2 = fmaf(hv.z, w2r[4 * jj + 2], q2);
      q3 = fmaf(hv.w, w2r[4 * jj + 3], q3);
    }
    const float theta = (q0 + q1) + (q2 + q3) + b2v;
    const float cv = __cosf(theta);   // lane (hb,i) holds cos(theta[i])

    // gather my gate group's 8 cos values (one latency event)
    const int gb8 = lbase + g * 8;
    const float e0 = __shfl(cv, gb8 + 0, 64);
    const float e1 = __shfl(cv, gb8 + 1, 64);
    const float e2 = __shfl(cv, gb8 + 2, 64);
    const float e3 = __shfl(cv, gb8 + 3, 64);
    const float e4 = __shfl(cv, gb8 + 4, 64);
    const float e5 = __shfl(cv, gb8 + 5, 64);
    const float e6 = __shfl(cv, gb8 + 6, 64);
    const float e7 = __shfl(cv, gb8 + 7, 64);
    float p = e0, s = e0;
    p *= e1; s += p;
    p *= e2; s += p;
    p *= e3; s += p;
    p *= e4; s += p;
    p *= e5; s += p;
    p *= e6; s += p;
    p *= e7; s += p;
    const float qv = s * 0.125f;

    // one quantum activation per lane (group 2: tanh = 2*sigmoid(2x)-1)
    const float qarg = (g == 2) ? (2.0f * qv) : qv;
    const float qs = sigmoid_f(qarg);
    const float av = (g == 2) ? (2.0f * qs - 1.0f) : qs;

    const float aF = __shfl(av, lbase + 0, 64);
    const float aI = __shfl(av, lbase + 8, 64);
    const float aG = __shfl(av, lbase + 16, 64);
    const float aO = __shfl(av, lbase + 24, 64);

    const float f  = 0.5f * (cf + aF);
    const float ii = 0.5f * (ci + aI);
    const float gg = 0.5f * (cg + aG);
    const float oo = 0.5f * (co + aO);

    c = fmaf(f, c, ii * gg);
    h = oo * tanh_f(c);

    // store h replicated into out[t][b][0..255]: 8 floats per lane
    float* ob = out + ((size_t)t * BATCH + b) * 256 + 8 * i;
    float4 hv4o; hv4o.x = h; hv4o.y = h; hv4o.z = h; hv4o.w = h;
    *(float4*)(ob) = hv4o;
    *(float4*)(ob + 4) = hv4o;
  }

  // final (hx, cx)
  float* hxp = out + (size_t)SEQ * BATCH * 256 + (size_t)b * 256 + 8 * i;
  float* cxp = hxp + (size_t)BATCH * 256;
  float4 hq2; hq2.x = h; hq2.y = h; hq2.z = h; hq2.w = h;
  float4 cq2; cq2.x = c; cq2.y = c; cq2.z = c; cq2.w = c;
  *(float4*)(hxp) = hq2; *(float4*)(hxp + 4) = hq2;
  *(float4*)(cxp) = cq2; *(float4*)(cxp + 4) = cq2;
}

// ---------------------------------------------------------------------------
extern "C" void kernel_launch(void* const* d_in, const int* in_sizes, int n_in,
                              void* d_out, int out_size, void* d_ws,
                              size_t ws_size, hipStream_t stream) {
  const float* X  = (const float*)d_in[0];
  const float* W1 = (const float*)d_in[1];
  const float* b1 = (const float*)d_in[2];
  const float* W2 = (const float*)d_in[3];
  const float* b2 = (const float*)d_in[4];
  const float* Wf = (const float*)d_in[5];
  const float* bf = (const float*)d_in[6];
  const float* Wi = (const float*)d_in[7];
  const float* bi = (const float*)d_in[8];
  const float* Wg = (const float*)d_in[9];
  const float* bg = (const float*)d_in[10];
  const float* Wo = (const float*)d_in[11];
  const float* bo = (const float*)d_in[12];

  float* ws  = (float*)d_ws;
  float* PRE = ws;
  float* aux = ws + AUX_OFF;
  float* out = (float*)d_out;

  prep_kernel<<<1, 256, 0, stream>>>(W1, Wf, Wi, Wg, Wo, bf, bi, bg, bo, aux);
  gemm_kernel<<<M_ROWS / 128, 256, 0, stream>>>(X, W1, b1, Wf, Wi, Wg, Wo,
                                                bf, bi, bg, bo, PRE);
  rec_kernel<<<BATCH / 2, 64, 0, stream>>>(PRE, W2, b2, aux, out);
}

// Round 8
// 762.117 us; speedup vs baseline: 2.8063x; 1.4495x over previous
//
#include <hip/hip_runtime.h>

#define SEQ 512
#define BATCH 256
#define INDIM 256
#define MLP 128
#define M_ROWS (SEQ * BATCH)        // 131072
#define PRE_STRIDE 136              // 128 mlp-pre + 4 gate-pre + 4 pad
#define AUX_OFF ((size_t)M_ROWS * PRE_STRIDE)  // in floats

// ---------------------------------------------------------------------------
// Kernel 1: prep — column sums of the recurrent halves of W1 and gate weights.
// ---------------------------------------------------------------------------
__global__ __launch_bounds__(256) void prep_kernel(
    const float* __restrict__ W1,
    const float* __restrict__ Wf, const float* __restrict__ Wi,
    const float* __restrict__ Wg, const float* __restrict__ Wo,
    const float* __restrict__ bf, const float* __restrict__ bi,
    const float* __restrict__ bg, const float* __restrict__ bo,
    float* __restrict__ aux) {
  const int tid = threadIdx.x;
  if (tid < 128) {
    float s = 0.f;
    for (int k = 0; k < 256; ++k) s += W1[(size_t)(256 + k) * 128 + tid];
    aux[tid] = s;
  } else if (tid < 132) {
    const int g = tid - 128;
    const float* w = (g == 0) ? Wf : (g == 1) ? Wi : (g == 2) ? Wg : Wo;
    float s = 0.f;
    for (int k = 0; k < 256; ++k) s += w[256 + k];
    aux[128 + g] = s;
  } else if (tid < 136) {
    const int g = tid - 132;
    const float* bp = (g == 0) ? bf : (g == 1) ? bi : (g == 2) ? bg : bo;
    aux[132 + g] = bp[0];
  }
}

// ---------------------------------------------------------------------------
// Kernel 2: big fp32 GEMM — R5 version verbatim (proven ~306 µs; R7's
// double-buffer regressed it: 2x LDS halved blocks/CU).
// ---------------------------------------------------------------------------
#define BK 16
#define LDX 132  // padded LDS row stride (words)

__global__ __launch_bounds__(256) void gemm_kernel(
    const float* __restrict__ X,    // [M_ROWS][256]
    const float* __restrict__ W1,   // [512][128] (only rows 0..255 used here)
    const float* __restrict__ b1p,  // [128]
    const float* __restrict__ Wf, const float* __restrict__ Wi,
    const float* __restrict__ Wg, const float* __restrict__ Wo,
    const float* __restrict__ bfp, const float* __restrict__ bip,
    const float* __restrict__ bgp, const float* __restrict__ bop,
    float* __restrict__ PRE) {
  __shared__ __align__(16) float Xs[BK * LDX];   // [kk][row], row-padded
  __shared__ __align__(16) float Ws[BK * LDX];   // [kk][col]
  __shared__ float Wgs[BK * 4];                  // [kk][gate]

  const int tid = threadIdx.x;
  const int blk = blockIdx.x;
  const int tx = tid & 15, ty = tid >> 4;       // 16x16 thread grid
  const int r_st = tid >> 1, kh = (tid & 1) * 8; // X staging role
  const int wk = tid >> 4, wn = (tid & 15) * 8;  // W staging role
  const int r2 = tid >> 1, gp = (tid & 1) * 2;   // gate compute role

  const size_t rowbase = (size_t)blk * 128;

  float acc[8][8] = {};
  float ga = 0.f, gb = 0.f;

  for (int kc = 0; kc < 256; kc += BK) {
    const float4 xa = *(const float4*)&X[(rowbase + r_st) * 256 + kc + kh];
    const float4 xb = *(const float4*)&X[(rowbase + r_st) * 256 + kc + kh + 4];
    const float4 wa = *(const float4*)&W1[(size_t)(kc + wk) * 128 + wn];
    const float4 wb = *(const float4*)&W1[(size_t)(kc + wk) * 128 + wn + 4];
    float wgv = 0.f;
    if (tid < 64) {
      const int kk = tid >> 2, g = tid & 3;
      const float* w = (g == 0) ? Wf : (g == 1) ? Wi : (g == 2) ? Wg : Wo;
      wgv = w[kc + kk];
    }
    __syncthreads();
    Xs[(kh + 0) * LDX + r_st] = xa.x;
    Xs[(kh + 1) * LDX + r_st] = xa.y;
    Xs[(kh + 2) * LDX + r_st] = xa.z;
    Xs[(kh + 3) * LDX + r_st] = xa.w;
    Xs[(kh + 4) * LDX + r_st] = xb.x;
    Xs[(kh + 5) * LDX + r_st] = xb.y;
    Xs[(kh + 6) * LDX + r_st] = xb.z;
    Xs[(kh + 7) * LDX + r_st] = xb.w;
    *(float4*)&Ws[wk * LDX + wn] = wa;
    *(float4*)&Ws[wk * LDX + wn + 4] = wb;
    if (tid < 64) Wgs[tid] = wgv;
    __syncthreads();

#pragma unroll
    for (int kk = 0; kk < BK; ++kk) {
      const float4 a0 = *(const float4*)&Xs[kk * LDX + ty * 8];
      const float4 a1 = *(const float4*)&Xs[kk * LDX + ty * 8 + 4];
      const float4 c0 = *(const float4*)&Ws[kk * LDX + tx * 8];
      const float4 c1 = *(const float4*)&Ws[kk * LDX + tx * 8 + 4];
      const float av[8] = {a0.x, a0.y, a0.z, a0.w, a1.x, a1.y, a1.z, a1.w};
      const float bv[8] = {c0.x, c0.y, c0.z, c0.w, c1.x, c1.y, c1.z, c1.w};
#pragma unroll
      for (int i = 0; i < 8; ++i)
#pragma unroll
        for (int j = 0; j < 8; ++j)
          acc[i][j] = fmaf(av[i], bv[j], acc[i][j]);
      const float xv = Xs[kk * LDX + r2];
      ga = fmaf(xv, Wgs[kk * 4 + gp], ga);
      gb = fmaf(xv, Wgs[kk * 4 + gp + 1], gb);
    }
  }

  float bias[8];
  {
    const float4 u0 = *(const float4*)&b1p[tx * 8];
    const float4 u1 = *(const float4*)&b1p[tx * 8 + 4];
    bias[0] = u0.x; bias[1] = u0.y; bias[2] = u0.z; bias[3] = u0.w;
    bias[4] = u1.x; bias[5] = u1.y; bias[6] = u1.z; bias[7] = u1.w;
  }
#pragma unroll
  for (int i = 0; i < 8; ++i) {
    const size_t row = rowbase + ty * 8 + i;
    float4 o0, o1;
    o0.x = acc[i][0] + bias[0]; o0.y = acc[i][1] + bias[1];
    o0.z = acc[i][2] + bias[2]; o0.w = acc[i][3] + bias[3];
    o1.x = acc[i][4] + bias[4]; o1.y = acc[i][5] + bias[5];
    o1.z = acc[i][6] + bias[6]; o1.w = acc[i][7] + bias[7];
    *(float4*)&PRE[row * PRE_STRIDE + tx * 8] = o0;
    *(float4*)&PRE[row * PRE_STRIDE + tx * 8 + 4] = o1;
  }
  {
    const float ab = (gp == 0) ? bfp[0] : bgp[0];
    const float bb2 = (gp == 0) ? bip[0] : bop[0];
    float2 og;
    og.x = ga + ab; og.y = gb + bb2;
    *(float2*)&PRE[(rowbase + r2) * PRE_STRIDE + 128 + gp] = og;
  }
}

// ---------------------------------------------------------------------------
// Kernel 3: serial recurrence. R7 post-mortem: VGPR budget is hard-capped at
// ~132 by this toolchain — all designs must fit. R5 64-lane layout retained
// (w2r[64] fits). DS-stage diet vs R5:
//  - NO explicit lgkmcnt(0) fence: DS instrs from one wave execute in order,
//    so the ds_write is serviced before the later ds_reads; the compiler
//    still inserts lgkm waits for read RESULTS. Compiler-barrier only.
//  - shfl_xor + gather8 fused into ONE 16-shfl pipelined burst on raw
//    partials; theta/cos computed per-lane redundantly (VALU is cheap,
//    DS latency is not).
//  - gather4 replaced by 4 v_readlane (uniform lanes 0/8/16/24; VALU pipe).
//  - prefetch depth 2 (saves 6 VGPRs; slack 2 steps >> HBM latency).
// ---------------------------------------------------------------------------
__device__ __forceinline__ float sigmoid_f(float x) {
  return __fdividef(1.0f, 1.0f + __expf(-x));
}
__device__ __forceinline__ float tanh_f(float x) {
  const float e = __expf(-2.0f * x);
  return __fdividef(1.0f - e, 1.0f + e);
}
__device__ __forceinline__ float readlane_f(float v, int lane) {
  return __int_as_float(__builtin_amdgcn_readlane(__float_as_int(v), lane));
}

__global__ __attribute__((amdgpu_waves_per_eu(1, 1))) __launch_bounds__(64)
void rec_kernel(
    const float* __restrict__ PRE, const float* __restrict__ W2,
    const float* __restrict__ b2, const float* __restrict__ aux,
    float* __restrict__ out) {
  __shared__ __align__(16) float h1s[128];

  const int l = threadIdx.x;
  const int b = blockIdx.x;
  const int m = l & 31, half = l >> 5;
  const int g = m >> 3;             // my gate group: 0=f 1=i 2=g 3=o
  const int g8 = g * 8;             // first column of my group

  // W2 fragment in registers: lane (m,half) holds W2[half*64+u][m]
  float w2r[64];
#pragma unroll
  for (int u = 0; u < 64; ++u) w2r[u] = W2[(size_t)(half * 64 + u) * 32 + m];
  // my group's 8 b2 entries (per-lane g -> VGPR loads, 16B aligned)
  const float4 b2a = *(const float4*)&b2[g8];
  const float4 b2b = *(const float4*)&b2[g8 + 4];
  const float2 s1 = *(const float2*)&aux[2 * l];
  const float4 sg = *(const float4*)&aux[128];  // sf, si, sg, so

  float h = 0.f, c = 0.f;

  const float* pr0 = PRE + (size_t)b * PRE_STRIDE;
  const size_t ts = (size_t)BATCH * PRE_STRIDE;

  // depth-2 rotating prefetch
  float2 p0 = *(const float2*)(pr0 + 0 * ts + 2 * l);
  float4 g0 = *(const float4*)(pr0 + 0 * ts + 128);
  float2 p1 = *(const float2*)(pr0 + 1 * ts + 2 * l);
  float4 g1 = *(const float4*)(pr0 + 1 * ts + 128);

  const float4* h1p = (const float4*)&h1s[half * 64];

  for (int t = 0; t < SEQ; ++t) {
    // h1 = relu(pre + h*s1)
    const float h10 = fmaxf(fmaf(h, s1.x, p0.x), 0.f);
    const float h11 = fmaxf(fmaf(h, s1.y, p0.y), 0.f);

    // publish h1 (the step's only LDS write); DS pipe is in-order per wave,
    // so the later ds_reads observe it without an explicit waitcnt.
    ((float2*)h1s)[l] = make_float2(h10, h11);
    asm volatile("" ::: "memory");  // compiler barrier only — no s_waitcnt

    // classical gates — independent VALU work placed to overlap LDS latency
    const float zf = fmaf(h, sg.x, g0.x);
    const float zi = fmaf(h, sg.y, g0.y);
    const float zg = fmaf(h, sg.z, g0.z);
    const float zo = fmaf(h, sg.w, g0.w);
    const float cf = sigmoid_f(zf);
    const float ci = sigmoid_f(zi);
    const float cg = tanh_f(zg);
    const float co = sigmoid_f(zo);
    // rotate prefetch (depth 2)
    p0 = p1; g0 = g1;
    const int tn = (t + 2 < SEQ) ? (t + 2) : (SEQ - 1);
    p1 = *(const float2*)(pr0 + (size_t)tn * ts + 2 * l);
    g1 = *(const float4*)(pr0 + (size_t)tn * ts + 128);

    // partial[m,half] = sum over my K-half of h1[j]*W2[j][m]
    float q0 = 0.f, q1 = 0.f, q2 = 0.f, q3 = 0.f;
#pragma unroll
    for (int jj = 0; jj < 16; ++jj) {
      const float4 hv = h1p[jj];
      q0 = fmaf(hv.x, w2r[4 * jj + 0], q0);
      q1 = fmaf(hv.y, w2r[4 * jj + 1], q1);
      q2 = fmaf(hv.z, w2r[4 * jj + 2], q2);
      q3 = fmaf(hv.w, w2r[4 * jj + 3], q3);
    }
    const float part = (q0 + q1) + (q2 + q3);

    // ONE pipelined 16-shfl burst: both halves' partials for my group's 8 m's
    const float a0 = __shfl(part, g8 + 0, 64), b0 = __shfl(part, 32 + g8 + 0, 64);
    const float a1 = __shfl(part, g8 + 1, 64), b1 = __shfl(part, 32 + g8 + 1, 64);
    const float a2 = __shfl(part, g8 + 2, 64), b2s = __shfl(part, 32 + g8 + 2, 64);
    const float a3 = __shfl(part, g8 + 3, 64), b3 = __shfl(part, 32 + g8 + 3, 64);
    const float a4 = __shfl(part, g8 + 4, 64), b4 = __shfl(part, 32 + g8 + 4, 64);
    const float a5 = __shfl(part, g8 + 5, 64), b5 = __shfl(part, 32 + g8 + 5, 64);
    const float a6 = __shfl(part, g8 + 6, 64), b6 = __shfl(part, 32 + g8 + 6, 64);
    const float a7 = __shfl(part, g8 + 7, 64), b7 = __shfl(part, 32 + g8 + 7, 64);

    // theta + cos, per-lane redundant (every lane evaluates ITS group)
    const float e0 = __cosf(a0 + b0 + b2a.x);
    const float e1 = __cosf(a1 + b1 + b2a.y);
    const float e2 = __cosf(a2 + b2s + b2a.z);
    const float e3 = __cosf(a3 + b3 + b2a.w);
    const float e4 = __cosf(a4 + b4 + b2b.x);
    const float e5 = __cosf(a5 + b5 + b2b.y);
    const float e6 = __cosf(a6 + b6 + b2b.z);
    const float e7 = __cosf(a7 + b7 + b2b.w);
    float p = e0, s = e0;
    p *= e1; s += p;
    p *= e2; s += p;
    p *= e3; s += p;
    p *= e4; s += p;
    p *= e5; s += p;
    p *= e6; s += p;
    p *= e7; s += p;
    const float qv = s * 0.125f;

    // one quantum activation per lane (group 2: tanh = 2*sigmoid(2x)-1)
    const float qarg = (g == 2) ? (2.0f * qv) : qv;
    const float qs = sigmoid_f(qarg);
    const float av = (g == 2) ? (2.0f * qs - 1.0f) : qs;

    // collect the 4 gate scalars via v_readlane (VALU, uniform lane indices)
    const float aF = readlane_f(av, 0);
    const float aI = readlane_f(av, 8);
    const float aG = readlane_f(av, 16);
    const float aO = readlane_f(av, 24);

    const float f  = 0.5f * (cf + aF);
    const float ii = 0.5f * (ci + aI);
    const float gg = 0.5f * (cg + aG);
    const float oo = 0.5f * (co + aO);

    c = fmaf(f, c, ii * gg);
    h = oo * tanh_f(c);

    float4 hv4o; hv4o.x = h; hv4o.y = h; hv4o.z = h; hv4o.w = h;
    *(float4*)(out + ((size_t)t * BATCH + b) * 256 + 4 * l) = hv4o;
  }

  // final (hx, cx)
  float4 hq; hq.x = h; hq.y = h; hq.z = h; hq.w = h;
  float4 cq; cq.x = c; cq.y = c; cq.z = c; cq.w = c;
  *(float4*)(out + (size_t)SEQ * BATCH * 256 + (size_t)b * 256 + 4 * l) = hq;
  *(float4*)(out + (size_t)SEQ * BATCH * 256 + (size_t)BATCH * 256 +
             (size_t)b * 256 + 4 * l) = cq;
}

// ---------------------------------------------------------------------------
extern "C" void kernel_launch(void* const* d_in, const int* in_sizes, int n_in,
                              void* d_out, int out_size, void* d_ws,
                              size_t ws_size, hipStream_t stream) {
  const float* X  = (const float*)d_in[0];
  const float* W1 = (const float*)d_in[1];
  const float* b1 = (const float*)d_in[2];
  const float* W2 = (const float*)d_in[3];
  const float* b2 = (const float*)d_in[4];
  const float* Wf = (const float*)d_in[5];
  const float* bf = (const float*)d_in[6];
  const float* Wi = (const float*)d_in[7];
  const float* bi = (const float*)d_in[8];
  const float* Wg = (const float*)d_in[9];
  const float* bg = (const float*)d_in[10];
  const float* Wo = (const float*)d_in[11];
  const float* bo = (const float*)d_in[12];

  float* ws  = (float*)d_ws;
  float* PRE = ws;
  float* aux = ws + AUX_OFF;
  float* out = (float*)d_out;

  prep_kernel<<<1, 256, 0, stream>>>(W1, Wf, Wi, Wg, Wo, bf, bi, bg, bo, aux);
  gemm_kernel<<<M_ROWS / 128, 256, 0, stream>>>(X, W1, b1, Wf, Wi, Wg, Wo,
                                                bf, bi, bg, bo, PRE);
  rec_kernel<<<BATCH, 64, 0, stream>>>(PRE, W2, b2, aux, out);
}